// Round 6
// baseline (617.442 us; speedup 1.0000x reference)
//
#include <hip/hip_runtime.h>
#include <cstdint>
#include <cstddef>

#define B8 8
#define LSEQ 2048
#define LC 2051
#define DMODEL 1024
#define DIM 2048
#define LPAD 2054           // 3 + 2048 + 3 zero-padded rows per batch
#define M2 16408            // B8*LC valid rows
#define M2P 16512           // padded to multiple of 128
#define CS 32               // scan chunk size
#define NCH 65              // ceil(2051/32)

typedef __attribute__((ext_vector_type(8))) short short8;
typedef __attribute__((ext_vector_type(4))) float floatx4;
typedef __attribute__((ext_vector_type(2))) float float2v;

// A_n = -exp(-n/3), n=0..15
__device__ __constant__ float AeT[16] = {
  -1.0f,          -0.71653131f, -0.51341712f, -0.36787944f,
  -0.26359714f,   -0.18887560f, -0.13533528f, -0.09697208f,
  -0.06948345f,   -0.04978707f, -0.03567399f, -0.02556154f,
  -0.01831564f,   -0.01312373f, -0.00940356f, -0.00673795f};

#define LOG2E 1.44269504088896f

__device__ __forceinline__ float bf2f(unsigned short h) {
  union { unsigned int u; float f; } v; v.u = ((unsigned int)h) << 16; return v.f;
}
__device__ __forceinline__ unsigned short f2bf(float f) {
  union { float f; unsigned int u; } v; v.f = f;
  unsigned int r = (v.u + 0x7FFFu + ((v.u >> 16) & 1u)) >> 16;
  return (unsigned short)r;
}

// ---- packed fp32 helpers (VOP3P). One scalar operand allowed per instr. ----
__device__ __forceinline__ float2v pk_mul_vv(float2v a, float2v b) {
  float2v d; asm("v_pk_mul_f32 %0, %1, %2" : "=v"(d) : "v"(a), "v"(b)); return d;
}
__device__ __forceinline__ float2v pk_mul_sv(float2v bs, float2v a) {   // bs wave-uniform (SGPR)
  float2v d; asm("v_pk_mul_f32 %0, %1, %2" : "=v"(d) : "s"(bs), "v"(a)); return d;
}
__device__ __forceinline__ float2v pk_fma_vvv(float2v a, float2v b, float2v c) {
  float2v d; asm("v_pk_fma_f32 %0, %1, %2, %3" : "=v"(d) : "v"(a), "v"(b), "v"(c)); return d;
}
__device__ __forceinline__ float2v pk_fma_vsv(float2v a, float2v bs, float2v c) { // bs uniform
  float2v d; asm("v_pk_fma_f32 %0, %1, %2, %3" : "=v"(d) : "v"(a), "s"(bs), "v"(c)); return d;
}
__device__ __forceinline__ float2v pk_add_vv(float2v a, float2v b) {
  float2v d; asm("v_pk_add_f32 %0, %1, %2" : "=v"(d) : "v"(a), "v"(b)); return d;
}
__device__ __forceinline__ float exp2_raw(float x) {   // 2^x
  float d; asm("v_exp_f32 %0, %1" : "=v"(d) : "v"(x)); return d;
}

// ---------------- fp32 -> bf16 convert (8 elems/thread) ----------------
__global__ __launch_bounds__(256) void cvt_f32_bf16(const float* __restrict__ in,
                                                    unsigned short* __restrict__ out,
                                                    int n8) {
  int i = blockIdx.x * 256 + threadIdx.x;
  if (i >= n8) return;
  const float4* p = (const float4*)in + (size_t)i * 2;
  float4 a = p[0], b = p[1];
  uint4 o;
  o.x = (unsigned)f2bf(a.x) | ((unsigned)f2bf(a.y) << 16);
  o.y = (unsigned)f2bf(a.z) | ((unsigned)f2bf(a.w) << 16);
  o.z = (unsigned)f2bf(b.x) | ((unsigned)f2bf(b.y) << 16);
  o.w = (unsigned)f2bf(b.z) | ((unsigned)f2bf(b.w) << 16);
  *((uint4*)out + i) = o;
}

// ---------------- zero the 6 pad rows per batch of xp ----------------
__global__ __launch_bounds__(256) void zero_pads(unsigned short* __restrict__ xp) {
  int i = blockIdx.x * 256 + threadIdx.x;      // 0..12287
  int b = i / 1536;
  int r6 = (i % 1536) / 256;
  int dd = (i % 256) * 8;
  int row = (r6 < 3) ? r6 : (2048 + r6);       // 0,1,2,2051,2052,2053
  uint4 z = make_uint4(0, 0, 0, 0);
  *(uint4*)(xp + ((size_t)b * LPAD + row) * DIM + dd) = z;
}

// ---------------- depthwise conv1d: xp(padded bf16) -> xc bf16 ----------------
__global__ __launch_bounds__(256) void conv_kernel(const unsigned short* __restrict__ xp,
                                                   const float* __restrict__ conv_w,
                                                   const float* __restrict__ conv_b,
                                                   unsigned short* __restrict__ xc) {
  const int tc = blockIdx.x, b = blockIdx.y;
  const int d0 = threadIdx.x * 8;
  const unsigned short* base = xp + ((size_t)b * LPAD + tc) * DIM + d0;

  float4 cw[8];
#pragma unroll
  for (int j = 0; j < 8; ++j) cw[j] = *(const float4*)(conv_w + (size_t)(d0 + j) * 4);

  float acc[8];
  const float4* cb4 = (const float4*)(conv_b + d0);
  float4 cb0 = cb4[0], cb1 = cb4[1];
  acc[0] = cb0.x; acc[1] = cb0.y; acc[2] = cb0.z; acc[3] = cb0.w;
  acc[4] = cb1.x; acc[5] = cb1.y; acc[6] = cb1.z; acc[7] = cb1.w;

#pragma unroll
  for (int k = 0; k < 4; ++k) {
    uint4 v = *(const uint4*)(base + (size_t)k * DIM);
    unsigned short e[8];
    e[0] = v.x & 0xffff; e[1] = v.x >> 16; e[2] = v.y & 0xffff; e[3] = v.y >> 16;
    e[4] = v.z & 0xffff; e[5] = v.z >> 16; e[6] = v.w & 0xffff; e[7] = v.w >> 16;
#pragma unroll
    for (int j = 0; j < 8; ++j)
      acc[j] = fmaf(bf2f(e[j]), ((const float*)&cw[j])[k], acc[j]);
  }
  uint4 o;
  o.x = (unsigned)f2bf(acc[0]) | ((unsigned)f2bf(acc[1]) << 16);
  o.y = (unsigned)f2bf(acc[2]) | ((unsigned)f2bf(acc[3]) << 16);
  o.z = (unsigned)f2bf(acc[4]) | ((unsigned)f2bf(acc[5]) << 16);
  o.w = (unsigned)f2bf(acc[6]) | ((unsigned)f2bf(acc[7]) << 16);
  *(uint4*)(xc + ((size_t)b * LC + tc) * DIM + d0) = o;
}

#define GAS(p) ((const __attribute__((address_space(1))) void*)(p))
#define LAS(p) ((__attribute__((address_space(3))) void*)(p))

// ---------------- small MFMA GEMM (m97 structure) kept for MODE 1 only ----------------
// MODE 1: xdbl -> fp32 [M2][48], cols<48
template <int NBM, int NBN, int LX>
__global__ __launch_bounds__(256) void gemm_bt(const unsigned short* __restrict__ A,
                                               const unsigned short* __restrict__ Bw,
                                               void* __restrict__ Cout, int K) {
  const int gid = blockIdx.x;
  const int xcd = gid & 7;
  const int j = gid >> 3;
  const int bmL = j % LX;
  const int bn = j / LX;
  const int bm = xcd * LX + bmL;
  if (bm >= NBM) return;

  __shared__ __align__(16) short As[128 * 32];
  __shared__ __align__(16) short Bs[128 * 32];
  const int tid = threadIdx.x;
  const int lane = tid & 63, wave = tid >> 6;
  const int wr = wave >> 1, wc = wave & 1;

  floatx4 acc[4][4];
#pragma unroll
  for (int i = 0; i < 4; ++i)
#pragma unroll
    for (int j2 = 0; j2 < 4; ++j2) acc[i][j2] = (floatx4){0.f, 0.f, 0.f, 0.f};

  const int sr = tid >> 2;
  const int sc = (tid & 3) * 8;
  const unsigned short* Ab = A + (size_t)(bm * 128 + sr) * K + sc;
  const unsigned short* Bb = Bw + (size_t)(bn * 128 + sr) * K + sc;
  const size_t rowK64 = (size_t)64 * K;

  const int fr = lane & 15;
  const int fk = (lane >> 4) * 8;
  const int aoff0 = (wr * 64 + fr) * 32 + fk;
  const int boff0 = (wc * 64 + fr) * 32 + fk;

  for (int k0 = 0; k0 < K; k0 += 32) {
    __syncthreads();
    __builtin_amdgcn_global_load_lds(GAS(Ab + k0),          LAS(As + tid * 8), 16, 0, 0);
    __builtin_amdgcn_global_load_lds(GAS(Ab + rowK64 + k0), LAS(As + 2048 + tid * 8), 16, 0, 0);
    __builtin_amdgcn_global_load_lds(GAS(Bb + k0),          LAS(Bs + tid * 8), 16, 0, 0);
    __builtin_amdgcn_global_load_lds(GAS(Bb + rowK64 + k0), LAS(Bs + 2048 + tid * 8), 16, 0, 0);
    __syncthreads();

    short8 af[4], bf[4];
#pragma unroll
    for (int mt = 0; mt < 4; ++mt) af[mt] = *(const short8*)&As[aoff0 + mt * 16 * 32];
#pragma unroll
    for (int nt = 0; nt < 4; ++nt) bf[nt] = *(const short8*)&Bs[boff0 + nt * 16 * 32];
#pragma unroll
    for (int mt = 0; mt < 4; ++mt)
#pragma unroll
      for (int nt = 0; nt < 4; ++nt)
        acc[mt][nt] = __builtin_amdgcn_mfma_f32_16x16x32_bf16(af[mt], bf[nt], acc[mt][nt], 0, 0, 0);
  }

  const int er = (lane >> 4) * 4, ec = lane & 15;
#pragma unroll
  for (int mt = 0; mt < 4; ++mt) {
#pragma unroll
    for (int nt = 0; nt < 4; ++nt) {
#pragma unroll
      for (int i = 0; i < 4; ++i) {
        int r = bm * 128 + wr * 64 + mt * 16 + er + i;
        int c = bn * 128 + wc * 64 + nt * 16 + ec;
        float v = acc[mt][nt][i];
        if (r < M2 && c < 48) ((float*)Cout)[(size_t)r * 48 + c] = v;
      }
    }
  }
}

// ---------------- deep-pipelined 256x256 GEMM (T1+T2+T3+T4+T5) ----------------
// C = A(MxK) @ B(NxK)^T.  BK=32, 4-buffer rotation, 2 phases/K-tile, 8 waves.
// Per phase: vmcnt(8) -> barrier -> stage tile t+3 (2 gload_lds) -> ds_read frags -> 16 MFMA.
// vmcnt(8): exactly the 4 younger half-stages (A/B of t+1,t+2 pattern) stay in flight.
// LDS swizzle: phys 16B-block = log block ^ (row&3); write side inverted on global src.
// MODE 0: C bf16 -> xp LPAD layout, +bias   (M=16384, N=2048, K=1024)
// MODE 2: C fp32 -> out, +bias, mask r<M2   (M=65*256 incl pad, N=1024, K=2048)
template <int MODE, int NBM, int NBN, int LX, int NT>
__global__ __launch_bounds__(512, 2) void gemm8p(const unsigned short* __restrict__ A,
                                                 const unsigned short* __restrict__ Bw,
                                                 const float* __restrict__ bias,
                                                 void* __restrict__ Cout) {
  constexpr int K = NT * 32;
  const int gid = blockIdx.x;
  const int xcd = gid & 7;
  const int jj = gid >> 3;
  const int bm = xcd * LX + (jj % LX);
  const int bn = jj / LX;
  if (bm >= NBM) return;

  __shared__ __align__(16) unsigned short lds[4][2][8192];   // 4 bufs x {A,B} x 16KB = 128KB

  const int tid = threadIdx.x;
  const int lane = tid & 63;
  const int wid = tid >> 6;         // 0..7
  const int wr = wid >> 2;          // M half
  const int wc = wid & 3;           // N quarter

  // staging: load L in {0,1}: LDS ushort off = L*4096 + tid*8; row = L*128 + tid/4;
  // phys block = tid&3 holds logical block (tid&3)^(row&3)
  const int srow0 = tid >> 2;
  const int logb0 = (tid & 3) ^ (srow0 & 3);           // row&3 same for row and row+128
  const unsigned short* Asrc0 = A  + (size_t)(bm * 256 + srow0)       * K + logb0 * 8;
  const unsigned short* Asrc1 = A  + (size_t)(bm * 256 + 128 + srow0) * K + logb0 * 8;
  const unsigned short* Bsrc0 = Bw + (size_t)(bn * 256 + srow0)       * K + logb0 * 8;
  const unsigned short* Bsrc1 = Bw + (size_t)(bn * 256 + 128 + srow0) * K + logb0 * 8;

  // fragment read offsets (ushort idx): row*32 + ((lane>>4)^(lane&3))*8, row = base + (lane&15)
  const int fr = lane & 15;
  const int xorb = ((lane >> 4) ^ (lane & 3)) * 8;
  int offA[8], offB[4];
#pragma unroll
  for (int m = 0; m < 8; ++m) offA[m] = (wr * 128 + m * 16 + fr) * 32 + xorb;
#pragma unroll
  for (int n = 0; n < 4; ++n) offB[n] = (wc * 64 + n * 16 + fr) * 32 + xorb;

  floatx4 acc[8][4];
#pragma unroll
  for (int m = 0; m < 8; ++m)
#pragma unroll
    for (int n = 0; n < 4; ++n) acc[m][n] = (floatx4){0.f, 0.f, 0.f, 0.f};

  auto STAGE = [&](int tile, int mat) {
    unsigned short* db = &lds[tile & 3][mat][0];
    const unsigned short* s0 = mat ? Bsrc0 : Asrc0;
    const unsigned short* s1 = mat ? Bsrc1 : Asrc1;
    __builtin_amdgcn_global_load_lds(GAS(s0 + (size_t)tile * 32), LAS(db + tid * 8), 16, 0, 0);
    __builtin_amdgcn_global_load_lds(GAS(s1 + (size_t)tile * 32), LAS(db + 4096 + tid * 8), 16, 0, 0);
  };

  // prologue: stage tiles 0..2 (order A(t),B(t) -> vmcnt counting matches steady state)
#pragma unroll
  for (int t = 0; t < 3; ++t) {
    if (t < NT) { STAGE(t, 0); STAGE(t, 1); }
  }

  for (int t = 0; t < NT; ++t) {
    const unsigned short* ldsA = &lds[t & 3][0][0];
    const unsigned short* ldsB = &lds[t & 3][1][0];
    // ---- phase 0: quadrant m0..3 ----
    asm volatile("s_waitcnt vmcnt(8)" ::: "memory");
    __builtin_amdgcn_s_barrier();
    if (t + 3 < NT) STAGE(t + 3, 0);
    short8 b0 = *(const short8*)&ldsB[offB[0]];
    short8 b1 = *(const short8*)&ldsB[offB[1]];
    short8 b2 = *(const short8*)&ldsB[offB[2]];
    short8 b3 = *(const short8*)&ldsB[offB[3]];
    {
      short8 a0 = *(const short8*)&ldsA[offA[0]];
      short8 a1 = *(const short8*)&ldsA[offA[1]];
      short8 a2 = *(const short8*)&ldsA[offA[2]];
      short8 a3 = *(const short8*)&ldsA[offA[3]];
      __builtin_amdgcn_s_setprio(1);
      acc[0][0] = __builtin_amdgcn_mfma_f32_16x16x32_bf16(a0, b0, acc[0][0], 0, 0, 0);
      acc[0][1] = __builtin_amdgcn_mfma_f32_16x16x32_bf16(a0, b1, acc[0][1], 0, 0, 0);
      acc[0][2] = __builtin_amdgcn_mfma_f32_16x16x32_bf16(a0, b2, acc[0][2], 0, 0, 0);
      acc[0][3] = __builtin_amdgcn_mfma_f32_16x16x32_bf16(a0, b3, acc[0][3], 0, 0, 0);
      acc[1][0] = __builtin_amdgcn_mfma_f32_16x16x32_bf16(a1, b0, acc[1][0], 0, 0, 0);
      acc[1][1] = __builtin_amdgcn_mfma_f32_16x16x32_bf16(a1, b1, acc[1][1], 0, 0, 0);
      acc[1][2] = __builtin_amdgcn_mfma_f32_16x16x32_bf16(a1, b2, acc[1][2], 0, 0, 0);
      acc[1][3] = __builtin_amdgcn_mfma_f32_16x16x32_bf16(a1, b3, acc[1][3], 0, 0, 0);
      acc[2][0] = __builtin_amdgcn_mfma_f32_16x16x32_bf16(a2, b0, acc[2][0], 0, 0, 0);
      acc[2][1] = __builtin_amdgcn_mfma_f32_16x16x32_bf16(a2, b1, acc[2][1], 0, 0, 0);
      acc[2][2] = __builtin_amdgcn_mfma_f32_16x16x32_bf16(a2, b2, acc[2][2], 0, 0, 0);
      acc[2][3] = __builtin_amdgcn_mfma_f32_16x16x32_bf16(a2, b3, acc[2][3], 0, 0, 0);
      acc[3][0] = __builtin_amdgcn_mfma_f32_16x16x32_bf16(a3, b0, acc[3][0], 0, 0, 0);
      acc[3][1] = __builtin_amdgcn_mfma_f32_16x16x32_bf16(a3, b1, acc[3][1], 0, 0, 0);
      acc[3][2] = __builtin_amdgcn_mfma_f32_16x16x32_bf16(a3, b2, acc[3][2], 0, 0, 0);
      acc[3][3] = __builtin_amdgcn_mfma_f32_16x16x32_bf16(a3, b3, acc[3][3], 0, 0, 0);
      __builtin_amdgcn_s_setprio(0);
    }
    // ---- phase 1: quadrant m4..7 ----
    asm volatile("s_waitcnt vmcnt(8)" ::: "memory");
    __builtin_amdgcn_s_barrier();
    if (t + 3 < NT) STAGE(t + 3, 1);
    {
      short8 a4 = *(const short8*)&ldsA[offA[4]];
      short8 a5 = *(const short8*)&ldsA[offA[5]];
      short8 a6 = *(const short8*)&ldsA[offA[6]];
      short8 a7 = *(const short8*)&ldsA[offA[7]];
      __builtin_amdgcn_s_setprio(1);
      acc[4][0] = __builtin_amdgcn_mfma_f32_16x16x32_bf16(a4, b0, acc[4][0], 0, 0, 0);
      acc[4][1] = __builtin_amdgcn_mfma_f32_16x16x32_bf16(a4, b1, acc[4][1], 0, 0, 0);
      acc[4][2] = __builtin_amdgcn_mfma_f32_16x16x32_bf16(a4, b2, acc[4][2], 0, 0, 0);
      acc[4][3] = __builtin_amdgcn_mfma_f32_16x16x32_bf16(a4, b3, acc[4][3], 0, 0, 0);
      acc[5][0] = __builtin_amdgcn_mfma_f32_16x16x32_bf16(a5, b0, acc[5][0], 0, 0, 0);
      acc[5][1] = __builtin_amdgcn_mfma_f32_16x16x32_bf16(a5, b1, acc[5][1], 0, 0, 0);
      acc[5][2] = __builtin_amdgcn_mfma_f32_16x16x32_bf16(a5, b2, acc[5][2], 0, 0, 0);
      acc[5][3] = __builtin_amdgcn_mfma_f32_16x16x32_bf16(a5, b3, acc[5][3], 0, 0, 0);
      acc[6][0] = __builtin_amdgcn_mfma_f32_16x16x32_bf16(a6, b0, acc[6][0], 0, 0, 0);
      acc[6][1] = __builtin_amdgcn_mfma_f32_16x16x32_bf16(a6, b1, acc[6][1], 0, 0, 0);
      acc[6][2] = __builtin_amdgcn_mfma_f32_16x16x32_bf16(a6, b2, acc[6][2], 0, 0, 0);
      acc[6][3] = __builtin_amdgcn_mfma_f32_16x16x32_bf16(a6, b3, acc[6][3], 0, 0, 0);
      acc[7][0] = __builtin_amdgcn_mfma_f32_16x16x32_bf16(a7, b0, acc[7][0], 0, 0, 0);
      acc[7][1] = __builtin_amdgcn_mfma_f32_16x16x32_bf16(a7, b1, acc[7][1], 0, 0, 0);
      acc[7][2] = __builtin_amdgcn_mfma_f32_16x16x32_bf16(a7, b2, acc[7][2], 0, 0, 0);
      acc[7][3] = __builtin_amdgcn_mfma_f32_16x16x32_bf16(a7, b3, acc[7][3], 0, 0, 0);
      __builtin_amdgcn_s_setprio(0);
    }
  }

  // ---- epilogue ----
  const int er = (lane >> 4) * 4, ec = lane & 15;
#pragma unroll
  for (int m = 0; m < 8; ++m) {
#pragma unroll
    for (int n = 0; n < 4; ++n) {
#pragma unroll
      for (int i = 0; i < 4; ++i) {
        int r = bm * 256 + wr * 128 + m * 16 + er + i;
        int c = bn * 256 + wc * 64 + n * 16 + ec;
        float v = acc[m][n][i];
        if constexpr (MODE == 0) {
          int bb = r >> 11, tt = r & 2047;
          ((unsigned short*)Cout)[((size_t)bb * LPAD + 3 + tt) * DIM + c] = f2bf(v + bias[c]);
        } else {
          if (r < M2) ((float*)Cout)[(size_t)r * DMODEL + c] = v + bias[c];
        }
      }
    }
  }
}

// ---------------- delta precompute: softplus(d_raw @ W_dt.T + b_dt) -> bf16 ----------------
__global__ __launch_bounds__(256) void delta_kernel(const float* __restrict__ xdbl,
                                                    const float* __restrict__ W_dt,
                                                    const float* __restrict__ b_dt,
                                                    unsigned short* __restrict__ delta) {
  const int d = blockIdx.y * 256 + threadIdx.x;
  const int r0 = blockIdx.x * 8;
  float wv[16];
  const float4* wp = (const float4*)(W_dt + (size_t)d * 16);
#pragma unroll
  for (int q = 0; q < 4; ++q) {
    float4 t = wp[q];
    wv[q * 4 + 0] = t.x; wv[q * 4 + 1] = t.y; wv[q * 4 + 2] = t.z; wv[q * 4 + 3] = t.w;
  }
  const float bd = b_dt[d];
#pragma unroll
  for (int j = 0; j < 8; ++j) {
    const float* dr = xdbl + (size_t)(r0 + j) * 48;   // uniform -> s_load
    float z0 = bd, z1 = 0.f, z2 = 0.f, z3 = 0.f;
#pragma unroll
    for (int n = 0; n < 16; n += 4) {
      z0 = fmaf(dr[n + 0], wv[n + 0], z0);
      z1 = fmaf(dr[n + 1], wv[n + 1], z1);
      z2 = fmaf(dr[n + 2], wv[n + 2], z2);
      z3 = fmaf(dr[n + 3], wv[n + 3], z3);
    }
    float z = (z0 + z1) + (z2 + z3);
    float dl = (z > 20.f) ? z : __logf(1.f + __expf(z));
    delta[(size_t)(r0 + j) * DIM + d] = f2bf(dl);
  }
}

// ---------------- chunked scan, pass 1: per-chunk (sumd, q) -> bf16 ----------------
__global__ __launch_bounds__(256) void scan_pass1(const unsigned short* __restrict__ xc,
                                                  const unsigned short* __restrict__ dl,
                                                  const float* __restrict__ xd,
                                                  unsigned short* __restrict__ sdbuf,
                                                  unsigned short* __restrict__ qbuf) {
  const int wid = __builtin_amdgcn_readfirstlane((int)(threadIdx.x >> 6));
  const int lane = threadIdx.x & 63;
  const int W = blockIdx.x * 4 + wid;
  const int dg = W & 31;
  const int rest = W >> 5;
  const int c = rest % NCH;
  const int b = rest / NCH;
  const int d = dg * 64 + lane;
  const int t0 = c * CS;
  const int nst = (t0 + CS <= LC) ? CS : (LC - t0);

  float2v A2L[8];
#pragma unroll
  for (int i = 0; i < 8; ++i)
    A2L[i] = (float2v){AeT[2 * i] * LOG2E, AeT[2 * i + 1] * LOG2E};

  float2v h2[8];
#pragma unroll
  for (int i = 0; i < 8; ++i) h2[i] = (float2v){0.f, 0.f};
  float sumd = 0.f;

  const size_t row0 = (size_t)b * LC + t0;
  const float* xdb = xd + row0 * 48 + 16;            // B cols (uniform -> s_load)
  const unsigned short* xcp = xc + row0 * DIM + d;
  const unsigned short* dp  = dl + row0 * DIM + d;

  float2v BA[8], BB[8];
#pragma unroll
  for (int j = 0; j < 8; ++j) BA[j] = *(const float2v*)(xdb + 2 * j);
  float d0v = bf2f(dp[0]), x0v = bf2f(xcp[0]);

  auto step = [&](const float2v (&Bv)[8], float dlt, float xcv) {
    sumd += dlt;
    float2v dlt2 = (float2v){dlt, dlt};
    float2v xcv2 = (float2v){xcv, xcv};
#pragma unroll
    for (int i = 0; i < 8; ++i) {
      float2v arg = pk_mul_vv(dlt2, A2L[i]);
      float e0 = exp2_raw(arg.x), e1 = exp2_raw(arg.y);
      float2v e2 = (float2v){e0, e1};
      h2[i] = pk_fma_vvv(h2[i], e2, pk_mul_sv(Bv[i], xcv2));
    }
  };

  for (int s = 0; s < nst; s += 2) {
    int s1 = (s + 1 < nst) ? s + 1 : s;
#pragma unroll
    for (int j = 0; j < 8; ++j) BB[j] = *(const float2v*)(xdb + (size_t)s1 * 48 + 2 * j);
    float d1v = bf2f(dp[(size_t)s1 * DIM]);
    float x1v = bf2f(xcp[(size_t)s1 * DIM]);
    step(BA, d0v, x0v);
    if (s + 1 >= nst) break;
    int s2 = (s + 2 < nst) ? s + 2 : s + 1;
#pragma unroll
    for (int j = 0; j < 8; ++j) BA[j] = *(const float2v*)(xdb + (size_t)s2 * 48 + 2 * j);
    d0v = bf2f(dp[(size_t)s2 * DIM]);
    x0v = bf2f(xcp[(size_t)s2 * DIM]);
    step(BB, d1v, x1v);
  }

  sdbuf[((size_t)(b * NCH + c) << 11) + d] = f2bf(sumd);
  const size_t base = ((size_t)(b * NCH + c) * 16) * 2048 + d;
#pragma unroll
  for (int i = 0; i < 8; ++i) {
    qbuf[base + ((size_t)(2 * i) << 11)]     = f2bf(h2[i].x);
    qbuf[base + ((size_t)(2 * i + 1) << 11)] = f2bf(h2[i].y);
  }
}

// ---------------- boundary scan: h across chunks; writes h_init over q ----------------
__global__ __launch_bounds__(64) void scan_boundary(const unsigned short* __restrict__ sdbuf,
                                                    unsigned short* __restrict__ qbuf) {
  const int d = blockIdx.x * 64 + threadIdx.x;
  const int b = blockIdx.y;
  float h[16];
#pragma unroll
  for (int n = 0; n < 16; ++n) h[n] = 0.f;
  for (int c = 0; c < NCH; ++c) {
    const float sd = bf2f(sdbuf[((size_t)(b * NCH + c) << 11) + d]);
    const size_t base = ((size_t)(b * NCH + c) * 16) * 2048 + d;
    float qv[16];
#pragma unroll
    for (int n = 0; n < 16; ++n) qv[n] = bf2f(qbuf[base + ((size_t)n << 11)]);
#pragma unroll
    for (int n = 0; n < 16; ++n) {
      float Pv = __expf(sd * AeT[n]);
      qbuf[base + ((size_t)n << 11)] = f2bf(h[n]);   // h at chunk start
      h[n] = fmaf(Pv, h[n], qv[n]);
    }
  }
}

// ---------------- chunked scan, pass 2: recompute with h_init, emit y ----------------
__global__ __launch_bounds__(256) void scan_pass2(const unsigned short* __restrict__ xc,
                                                  const unsigned short* __restrict__ dl,
                                                  const float* __restrict__ xd,
                                                  const unsigned short* __restrict__ hinit,
                                                  unsigned short* __restrict__ y) {
  const int wid = __builtin_amdgcn_readfirstlane((int)(threadIdx.x >> 6));
  const int lane = threadIdx.x & 63;
  const int W = blockIdx.x * 4 + wid;
  const int dg = W & 31;
  const int rest = W >> 5;
  const int c = rest % NCH;
  const int b = rest / NCH;
  const int d = dg * 64 + lane;
  const int t0 = c * CS;
  const int nst = (t0 + CS <= LC) ? CS : (LC - t0);

  float2v A2L[8];
#pragma unroll
  for (int i = 0; i < 8; ++i)
    A2L[i] = (float2v){AeT[2 * i] * LOG2E, AeT[2 * i + 1] * LOG2E};

  const size_t base = ((size_t)(b * NCH + c) * 16) * 2048 + d;
  float2v h2[8];
#pragma unroll
  for (int i = 0; i < 8; ++i)
    h2[i] = (float2v){bf2f(hinit[base + ((size_t)(2 * i) << 11)]),
                      bf2f(hinit[base + ((size_t)(2 * i + 1) << 11)])};

  const size_t row0 = (size_t)b * LC + t0;
  const float* xdb = xd + row0 * 48 + 16;            // B at [j], C at [16+j]
  const unsigned short* xcp = xc + row0 * DIM + d;
  const unsigned short* dp  = dl + row0 * DIM + d;
  unsigned short* yp = y + row0 * DIM + d;

  float2v BA[8], CA[8], BB[8], CB[8];
#pragma unroll
  for (int j = 0; j < 8; ++j) {
    BA[j] = *(const float2v*)(xdb + 2 * j);
    CA[j] = *(const float2v*)(xdb + 16 + 2 * j);
  }
  float d0v = bf2f(dp[0]), x0v = bf2f(xcp[0]);

  auto step = [&](const float2v (&Bv)[8], const float2v (&Cv)[8], float dlt, float xcv, int s) {
    float2v dlt2 = (float2v){dlt, dlt};
    float2v xcv2 = (float2v){xcv, xcv};
    float2v y2[4];
#pragma unroll
    for (int i = 0; i < 4; ++i) y2[i] = (float2v){0.f, 0.f};
#pragma unroll
    for (int i = 0; i < 8; ++i) {
      float2v arg = pk_mul_vv(dlt2, A2L[i]);
      float e0 = exp2_raw(arg.x), e1 = exp2_raw(arg.y);
      float2v e2 = (float2v){e0, e1};
      h2[i] = pk_fma_vvv(h2[i], e2, pk_mul_sv(Bv[i], xcv2));
      y2[i & 3] = pk_fma_vsv(h2[i], Cv[i], y2[i & 3]);
    }
    float2v s01 = pk_add_vv(y2[0], y2[1]);
    float2v s23 = pk_add_vv(y2[2], y2[3]);
    float2v st = pk_add_vv(s01, s23);
    yp[(size_t)s * DIM] = f2bf(st.x + st.y);
  };

  for (int s = 0; s < nst; s += 2) {
    int s1 = (s + 1 < nst) ? s + 1 : s;
#pragma unroll
    for (int j = 0; j < 8; ++j) {
      BB[j] = *(const float2v*)(xdb + (size_t)s1 * 48 + 2 * j);
      CB[j] = *(const float2v*)(xdb + (size_t)s1 * 48 + 16 + 2 * j);
    }
    float d1v = bf2f(dp[(size_t)s1 * DIM]);
    float x1v = bf2f(xcp[(size_t)s1 * DIM]);
    step(BA, CA, d0v, x0v, s);
    if (s + 1 >= nst) break;
    int s2 = (s + 2 < nst) ? s + 2 : s + 1;
#pragma unroll
    for (int j = 0; j < 8; ++j) {
      BA[j] = *(const float2v*)(xdb + (size_t)s2 * 48 + 2 * j);
      CA[j] = *(const float2v*)(xdb + (size_t)s2 * 48 + 16 + 2 * j);
    }
    d0v = bf2f(dp[(size_t)s2 * DIM]);
    x0v = bf2f(xcp[(size_t)s2 * DIM]);
    step(BB, CB, d1v, x1v, s + 1);
  }
}

// ---------------- launch ----------------
extern "C" void kernel_launch(void* const* d_in, const int* in_sizes, int n_in,
                              void* d_out, int out_size, void* d_ws, size_t ws_size,
                              hipStream_t stream) {
  const float* x      = (const float*)d_in[0];
  const float* W_in   = (const float*)d_in[1];
  const float* b_in   = (const float*)d_in[2];
  const float* conv_w = (const float*)d_in[3];
  const float* conv_b = (const float*)d_in[4];
  const float* W_x    = (const float*)d_in[5];
  const float* W_dt   = (const float*)d_in[6];
  const float* b_dt   = (const float*)d_in[7];
  const float* W_out  = (const float*)d_in[8];
  const float* b_out  = (const float*)d_in[9];

  char* w = (char*)d_ws;
  // region 0 (67.63 MB): xp (LPAD layout) -> delta [M2P][DIM] -> y (in-place over delta)
  unsigned short* xp    = (unsigned short*)w;
  unsigned short* delta = (unsigned short*)w;
  unsigned short* ybuf  = (unsigned short*)w;
  size_t off = (size_t)M2P * DIM * 2;                                  // 67,633,152
  unsigned short* xcb  = (unsigned short*)(w + off); off += (size_t)M2P * DIM * 2;
  size_t xA_off = off;                                                 // 135,266,304
  unsigned short* xA   = (unsigned short*)(w + off); off += (size_t)16384 * 1024 * 2;
  unsigned short* wInB = (unsigned short*)(w + off); off += (size_t)2048 * 1024 * 2;
  unsigned short* wOutB= (unsigned short*)(w + off); off += (size_t)1024 * 2048 * 2;
  unsigned short* wXB  = (unsigned short*)(w + off); off += (size_t)128 * 2048 * 2;
  float* xdbl          = (float*)(w + off);          off += (size_t)M2 * 48 * 4;
  // sdbuf (2.13 MB bf16) + qbuf (34.08 MB bf16) reuse xA+wInB region (dead after gemm1)
  unsigned short* sdbuf = (unsigned short*)(w + xA_off);
  unsigned short* qbuf  = (unsigned short*)(w + xA_off + (size_t)B8 * NCH * 2048 * 2);
  (void)ws_size; (void)in_sizes; (void)n_in; (void)out_size;

  cvt_f32_bf16<<<8192, 256, 0, stream>>>(x, xA, 2097152);
  cvt_f32_bf16<<<1024, 256, 0, stream>>>(W_in, wInB, 262144);
  cvt_f32_bf16<<<1024, 256, 0, stream>>>(W_out, wOutB, 262144);
  cvt_f32_bf16<<<48,   256, 0, stream>>>(W_x, wXB, 12288);
  zero_pads<<<48, 256, 0, stream>>>(xp);

  // deep-pipelined GEMMs: grid = 8 * LX * NBN (XCD-banded remap inside)
  gemm8p<0, 64, 8, 8, 32><<<512, 512, 0, stream>>>(xA, wInB, b_in, xp);
  conv_kernel<<<dim3(LC, B8), 256, 0, stream>>>(xp, conv_w, conv_b, xcb);
  gemm_bt<129, 1, 17><<<136, 256, 0, stream>>>(xcb, wXB, xdbl, 2048);
  delta_kernel<<<dim3(2051, 8), 256, 0, stream>>>(xdbl, W_dt, b_dt, delta);

  scan_pass1<<<4160, 256, 0, stream>>>(xcb, delta, xdbl, sdbuf, qbuf);
  scan_boundary<<<dim3(32, B8), 64, 0, stream>>>(sdbuf, qbuf);
  scan_pass2<<<4160, 256, 0, stream>>>(xcb, delta, xdbl, qbuf, ybuf);

  gemm8p<2, 65, 4, 9, 64><<<288, 512, 0, stream>>>(ybuf, wOutB, b_out, (float*)d_out);
}

// Round 7
// 612.253 us; speedup vs baseline: 1.0085x; 1.0085x over previous
//
#include <hip/hip_runtime.h>
#include <cstdint>
#include <cstddef>

#define B8 8
#define LSEQ 2048
#define LC 2051
#define DMODEL 1024
#define DIM 2048
#define LPAD 2054           // 3 + 2048 + 3 zero-padded rows per batch
#define M2 16408            // B8*LC valid rows
#define M2P 16512           // padded to multiple of 128
#define CS 32               // scan chunk size
#define NCH 65              // ceil(2051/32)

typedef __attribute__((ext_vector_type(8))) short short8;
typedef __attribute__((ext_vector_type(4))) float floatx4;
typedef __attribute__((ext_vector_type(2))) float float2v;
typedef __attribute__((address_space(3))) unsigned short lds_ushort;

// A_n = -exp(-n/3), n=0..15
__device__ __constant__ float AeT[16] = {
  -1.0f,          -0.71653131f, -0.51341712f, -0.36787944f,
  -0.26359714f,   -0.18887560f, -0.13533528f, -0.09697208f,
  -0.06948345f,   -0.04978707f, -0.03567399f, -0.02556154f,
  -0.01831564f,   -0.01312373f, -0.00940356f, -0.00673795f};

#define LOG2E 1.44269504088896f

__device__ __forceinline__ float bf2f(unsigned short h) {
  union { unsigned int u; float f; } v; v.u = ((unsigned int)h) << 16; return v.f;
}
__device__ __forceinline__ unsigned short f2bf(float f) {
  union { float f; unsigned int u; } v; v.f = f;
  unsigned int r = (v.u + 0x7FFFu + ((v.u >> 16) & 1u)) >> 16;
  return (unsigned short)r;
}

// ---- packed fp32 helpers (VOP3P). One scalar operand allowed per instr. ----
__device__ __forceinline__ float2v pk_mul_vv(float2v a, float2v b) {
  float2v d; asm("v_pk_mul_f32 %0, %1, %2" : "=v"(d) : "v"(a), "v"(b)); return d;
}
__device__ __forceinline__ float2v pk_mul_sv(float2v bs, float2v a) {   // bs wave-uniform (SGPR)
  float2v d; asm("v_pk_mul_f32 %0, %1, %2" : "=v"(d) : "s"(bs), "v"(a)); return d;
}
__device__ __forceinline__ float2v pk_fma_vvv(float2v a, float2v b, float2v c) {
  float2v d; asm("v_pk_fma_f32 %0, %1, %2, %3" : "=v"(d) : "v"(a), "v"(b), "v"(c)); return d;
}
__device__ __forceinline__ float2v pk_fma_vsv(float2v a, float2v bs, float2v c) { // bs uniform
  float2v d; asm("v_pk_fma_f32 %0, %1, %2, %3" : "=v"(d) : "v"(a), "s"(bs), "v"(c)); return d;
}
__device__ __forceinline__ float2v pk_add_vv(float2v a, float2v b) {
  float2v d; asm("v_pk_add_f32 %0, %1, %2" : "=v"(d) : "v"(a), "v"(b)); return d;
}
__device__ __forceinline__ float exp2_raw(float x) {   // 2^x
  float d; asm("v_exp_f32 %0, %1" : "=v"(d) : "v"(x)); return d;
}

// ---- opaque LDS read: compiler cannot alias-track this against global_load_lds,
// so it cannot insert a conservative vmcnt(0) before it (the round-6 pipeline killer).
__device__ __forceinline__ short8 ds_read_b128_(const lds_ushort* p) {
  floatx4 d;
  unsigned addr = (unsigned)(size_t)p;     // AS(3) ptr -> 32-bit LDS offset
  asm volatile("ds_read_b128 %0, %1" : "=v"(d) : "v"(addr));
  return __builtin_bit_cast(short8, d);
}

// ---------------- fp32 -> bf16 convert (8 elems/thread) ----------------
__global__ __launch_bounds__(256) void cvt_f32_bf16(const float* __restrict__ in,
                                                    unsigned short* __restrict__ out,
                                                    int n8) {
  int i = blockIdx.x * 256 + threadIdx.x;
  if (i >= n8) return;
  const float4* p = (const float4*)in + (size_t)i * 2;
  float4 a = p[0], b = p[1];
  uint4 o;
  o.x = (unsigned)f2bf(a.x) | ((unsigned)f2bf(a.y) << 16);
  o.y = (unsigned)f2bf(a.z) | ((unsigned)f2bf(a.w) << 16);
  o.z = (unsigned)f2bf(b.x) | ((unsigned)f2bf(b.y) << 16);
  o.w = (unsigned)f2bf(b.z) | ((unsigned)f2bf(b.w) << 16);
  *((uint4*)out + i) = o;
}

// ---------------- zero the 6 pad rows per batch of xp ----------------
__global__ __launch_bounds__(256) void zero_pads(unsigned short* __restrict__ xp) {
  int i = blockIdx.x * 256 + threadIdx.x;      // 0..12287
  int b = i / 1536;
  int r6 = (i % 1536) / 256;
  int dd = (i % 256) * 8;
  int row = (r6 < 3) ? r6 : (2048 + r6);       // 0,1,2,2051,2052,2053
  uint4 z = make_uint4(0, 0, 0, 0);
  *(uint4*)(xp + ((size_t)b * LPAD + row) * DIM + dd) = z;
}

// ---------------- depthwise conv1d: xp(padded bf16) -> xc bf16 ----------------
__global__ __launch_bounds__(256) void conv_kernel(const unsigned short* __restrict__ xp,
                                                   const float* __restrict__ conv_w,
                                                   const float* __restrict__ conv_b,
                                                   unsigned short* __restrict__ xc) {
  const int tc = blockIdx.x, b = blockIdx.y;
  const int d0 = threadIdx.x * 8;
  const unsigned short* base = xp + ((size_t)b * LPAD + tc) * DIM + d0;

  float4 cw[8];
#pragma unroll
  for (int j = 0; j < 8; ++j) cw[j] = *(const float4*)(conv_w + (size_t)(d0 + j) * 4);

  float acc[8];
  const float4* cb4 = (const float4*)(conv_b + d0);
  float4 cb0 = cb4[0], cb1 = cb4[1];
  acc[0] = cb0.x; acc[1] = cb0.y; acc[2] = cb0.z; acc[3] = cb0.w;
  acc[4] = cb1.x; acc[5] = cb1.y; acc[6] = cb1.z; acc[7] = cb1.w;

#pragma unroll
  for (int k = 0; k < 4; ++k) {
    uint4 v = *(const uint4*)(base + (size_t)k * DIM);
    unsigned short e[8];
    e[0] = v.x & 0xffff; e[1] = v.x >> 16; e[2] = v.y & 0xffff; e[3] = v.y >> 16;
    e[4] = v.z & 0xffff; e[5] = v.z >> 16; e[6] = v.w & 0xffff; e[7] = v.w >> 16;
#pragma unroll
    for (int j = 0; j < 8; ++j)
      acc[j] = fmaf(bf2f(e[j]), ((const float*)&cw[j])[k], acc[j]);
  }
  uint4 o;
  o.x = (unsigned)f2bf(acc[0]) | ((unsigned)f2bf(acc[1]) << 16);
  o.y = (unsigned)f2bf(acc[2]) | ((unsigned)f2bf(acc[3]) << 16);
  o.z = (unsigned)f2bf(acc[4]) | ((unsigned)f2bf(acc[5]) << 16);
  o.w = (unsigned)f2bf(acc[6]) | ((unsigned)f2bf(acc[7]) << 16);
  *(uint4*)(xc + ((size_t)b * LC + tc) * DIM + d0) = o;
}

#define GAS(p) ((const __attribute__((address_space(1))) void*)(p))
#define LAS(p) ((__attribute__((address_space(3))) void*)(p))

// ---------------- small MFMA GEMM (m97 structure) kept for MODE 1 only ----------------
template <int NBM, int NBN, int LX>
__global__ __launch_bounds__(256) void gemm_bt(const unsigned short* __restrict__ A,
                                               const unsigned short* __restrict__ Bw,
                                               void* __restrict__ Cout, int K) {
  const int gid = blockIdx.x;
  const int xcd = gid & 7;
  const int j = gid >> 3;
  const int bmL = j % LX;
  const int bn = j / LX;
  const int bm = xcd * LX + bmL;
  if (bm >= NBM) return;

  __shared__ __align__(16) short As[128 * 32];
  __shared__ __align__(16) short Bs[128 * 32];
  const int tid = threadIdx.x;
  const int lane = tid & 63, wave = tid >> 6;
  const int wr = wave >> 1, wc = wave & 1;

  floatx4 acc[4][4];
#pragma unroll
  for (int i = 0; i < 4; ++i)
#pragma unroll
    for (int j2 = 0; j2 < 4; ++j2) acc[i][j2] = (floatx4){0.f, 0.f, 0.f, 0.f};

  const int sr = tid >> 2;
  const int sc = (tid & 3) * 8;
  const unsigned short* Ab = A + (size_t)(bm * 128 + sr) * K + sc;
  const unsigned short* Bb = Bw + (size_t)(bn * 128 + sr) * K + sc;
  const size_t rowK64 = (size_t)64 * K;

  const int fr = lane & 15;
  const int fk = (lane >> 4) * 8;
  const int aoff0 = (wr * 64 + fr) * 32 + fk;
  const int boff0 = (wc * 64 + fr) * 32 + fk;

  for (int k0 = 0; k0 < K; k0 += 32) {
    __syncthreads();
    __builtin_amdgcn_global_load_lds(GAS(Ab + k0),          LAS(As + tid * 8), 16, 0, 0);
    __builtin_amdgcn_global_load_lds(GAS(Ab + rowK64 + k0), LAS(As + 2048 + tid * 8), 16, 0, 0);
    __builtin_amdgcn_global_load_lds(GAS(Bb + k0),          LAS(Bs + tid * 8), 16, 0, 0);
    __builtin_amdgcn_global_load_lds(GAS(Bb + rowK64 + k0), LAS(Bs + 2048 + tid * 8), 16, 0, 0);
    __syncthreads();

    short8 af[4], bf[4];
#pragma unroll
    for (int mt = 0; mt < 4; ++mt) af[mt] = *(const short8*)&As[aoff0 + mt * 16 * 32];
#pragma unroll
    for (int nt = 0; nt < 4; ++nt) bf[nt] = *(const short8*)&Bs[boff0 + nt * 16 * 32];
#pragma unroll
    for (int mt = 0; mt < 4; ++mt)
#pragma unroll
      for (int nt = 0; nt < 4; ++nt)
        acc[mt][nt] = __builtin_amdgcn_mfma_f32_16x16x32_bf16(af[mt], bf[nt], acc[mt][nt], 0, 0, 0);
  }

  const int er = (lane >> 4) * 4, ec = lane & 15;
#pragma unroll
  for (int mt = 0; mt < 4; ++mt) {
#pragma unroll
    for (int nt = 0; nt < 4; ++nt) {
#pragma unroll
      for (int i = 0; i < 4; ++i) {
        int r = bm * 128 + wr * 64 + mt * 16 + er + i;
        int c = bn * 128 + wc * 64 + nt * 16 + ec;
        float v = acc[mt][nt][i];
        if (r < M2 && c < 48) ((float*)Cout)[(size_t)r * 48 + c] = v;
      }
    }
  }
}

// ---------------- deep-pipelined 256x256 GEMM, BK=32, 4-buffer rotation ----------------
// Per K-tile (1 phase): vmcnt(8/4/0) -> s_barrier -> stage t+3 (4 gload_lds, linear LDS,
// inverse-swizzled global src) -> 12 opaque asm ds_read_b128 (swizzled addr) ->
// lgkmcnt(0)+sched_barrier -> setprio(1) + 32 MFMA. Loads stay in flight 3 tiles (~>HBM lat).
// Swizzle: phys_kblk = log_kblk ^ ((row>>1)&3)  (64B rows -> read banks = lane&7, 2-way free).
// MODE 0: C bf16 -> xp LPAD layout, +bias   (M=16384, N=2048, K=1024)
// MODE 2: C fp32 -> out, +bias, mask r<M2   (M=16640 incl pad reads, N=1024, K=2048)
template <int MODE, int NBM, int NBN, int LX, int NT>
__global__ __launch_bounds__(512, 2) void gemm8p(const unsigned short* __restrict__ A,
                                                 const unsigned short* __restrict__ Bw,
                                                 const float* __restrict__ bias,
                                                 void* __restrict__ Cout) {
  constexpr int K = NT * 32;
  const int gid = blockIdx.x;
  const int xcd = gid & 7;
  const int jj = gid >> 3;
  const int bm = xcd * LX + (jj % LX);
  const int bn = jj / LX;
  if (bm >= NBM) return;

  __shared__ __align__(16) unsigned short lds[4][2][8192];   // 4 bufs x {A,B} x 16KB = 128KB

  const int tid = threadIdx.x;
  const int lane = tid & 63;
  const int wid = tid >> 6;         // 0..7
  const int wr = wid >> 2;          // M half (rows wr*128..+128)
  const int wc = wid & 3;           // N quarter (cols wc*64..+64)

  // staging: thread covers lines {tid, 512+tid} of each 1024-line (16KB) tile.
  // line -> row = line>>2, phys_blk = line&3; logical blk = phys ^ ((row>>1)&3).
  const int srow = tid >> 2;                          // 0..127
  const int sblk = (tid & 3) ^ ((tid >> 3) & 3);      // inverse swizzle on global src
  const unsigned short* As0 = A  + (size_t)(bm * 256 + srow)       * K + sblk * 8;
  const unsigned short* As1 = A  + (size_t)(bm * 256 + 128 + srow) * K + sblk * 8;
  const unsigned short* Bs0 = Bw + (size_t)(bn * 256 + srow)       * K + sblk * 8;
  const unsigned short* Bs1 = Bw + (size_t)(bn * 256 + 128 + srow) * K + sblk * 8;

  // fragment offsets (ushort units) within a 16KB tile: row*32 + phys_blk*8
  const int fr = lane & 15;
  const int physb = (lane >> 4) ^ ((lane >> 1) & 3);
  int offA[8], offB[4];
#pragma unroll
  for (int m = 0; m < 8; ++m) offA[m] = (wr * 128 + m * 16 + fr) * 32 + physb * 8;
#pragma unroll
  for (int n = 0; n < 4; ++n) offB[n] = (wc * 64 + n * 16 + fr) * 32 + physb * 8;

  floatx4 acc[8][4];
#pragma unroll
  for (int m = 0; m < 8; ++m)
#pragma unroll
    for (int n = 0; n < 4; ++n) acc[m][n] = (floatx4){0.f, 0.f, 0.f, 0.f};

  auto STAGE = [&](int t) {
    const int koff = t * 32;
    unsigned short* dA = &lds[t & 3][0][0];
    unsigned short* dB = &lds[t & 3][1][0];
    __builtin_amdgcn_global_load_lds(GAS(As0 + koff), LAS(dA + tid * 8), 16, 0, 0);
    __builtin_amdgcn_global_load_lds(GAS(As1 + koff), LAS(dA + 4096 + tid * 8), 16, 0, 0);
    __builtin_amdgcn_global_load_lds(GAS(Bs0 + koff), LAS(dB + tid * 8), 16, 0, 0);
    __builtin_amdgcn_global_load_lds(GAS(Bs1 + koff), LAS(dB + 4096 + tid * 8), 16, 0, 0);
  };

  STAGE(0); STAGE(1); STAGE(2);     // 12 loads in flight

  for (int t = 0; t < NT; ++t) {
    // wait for tile t's 4 loads: outstanding after them = 4 * (#staged tiles beyond t)
    if (t + 2 < NT)      asm volatile("s_waitcnt vmcnt(8)");
    else if (t + 1 < NT) asm volatile("s_waitcnt vmcnt(4)");
    else                 asm volatile("s_waitcnt vmcnt(0)");
    __builtin_amdgcn_s_barrier();
    if (t + 3 < NT) STAGE(t + 3);

    const lds_ushort* tA = (const lds_ushort*)LAS(&lds[t & 3][0][0]);
    const lds_ushort* tB = (const lds_ushort*)LAS(&lds[t & 3][1][0]);
    short8 bf[4], af[8];
#pragma unroll
    for (int n = 0; n < 4; ++n) bf[n] = ds_read_b128_(tB + offB[n]);
#pragma unroll
    for (int m = 0; m < 8; ++m) af[m] = ds_read_b128_(tA + offA[m]);
    asm volatile("s_waitcnt lgkmcnt(0)");
    __builtin_amdgcn_sched_barrier(0);

    __builtin_amdgcn_s_setprio(1);
#pragma unroll
    for (int m = 0; m < 8; ++m)
#pragma unroll
      for (int n = 0; n < 4; ++n)
        acc[m][n] = __builtin_amdgcn_mfma_f32_16x16x32_bf16(af[m], bf[n], acc[m][n], 0, 0, 0);
    __builtin_amdgcn_s_setprio(0);
  }

  // ---- epilogue ----
  const int er = (lane >> 4) * 4, ec = lane & 15;
#pragma unroll
  for (int m = 0; m < 8; ++m) {
#pragma unroll
    for (int n = 0; n < 4; ++n) {
#pragma unroll
      for (int i = 0; i < 4; ++i) {
        int r = bm * 256 + wr * 128 + m * 16 + er + i;
        int c = bn * 256 + wc * 64 + n * 16 + ec;
        float v = acc[m][n][i];
        if constexpr (MODE == 0) {
          int bb = r >> 11, tt = r & 2047;
          ((unsigned short*)Cout)[((size_t)bb * LPAD + 3 + tt) * DIM + c] = f2bf(v + bias[c]);
        } else {
          if (r < M2) ((float*)Cout)[(size_t)r * DMODEL + c] = v + bias[c];
        }
      }
    }
  }
}

// ---------------- delta precompute: softplus(d_raw @ W_dt.T + b_dt) -> bf16 ----------------
__global__ __launch_bounds__(256) void delta_kernel(const float* __restrict__ xdbl,
                                                    const float* __restrict__ W_dt,
                                                    const float* __restrict__ b_dt,
                                                    unsigned short* __restrict__ delta) {
  const int d = blockIdx.y * 256 + threadIdx.x;
  const int r0 = blockIdx.x * 8;
  float wv[16];
  const float4* wp = (const float4*)(W_dt + (size_t)d * 16);
#pragma unroll
  for (int q = 0; q < 4; ++q) {
    float4 t = wp[q];
    wv[q * 4 + 0] = t.x; wv[q * 4 + 1] = t.y; wv[q * 4 + 2] = t.z; wv[q * 4 + 3] = t.w;
  }
  const float bd = b_dt[d];
#pragma unroll
  for (int j = 0; j < 8; ++j) {
    const float* dr = xdbl + (size_t)(r0 + j) * 48;   // uniform -> s_load
    float z0 = bd, z1 = 0.f, z2 = 0.f, z3 = 0.f;
#pragma unroll
    for (int n = 0; n < 16; n += 4) {
      z0 = fmaf(dr[n + 0], wv[n + 0], z0);
      z1 = fmaf(dr[n + 1], wv[n + 1], z1);
      z2 = fmaf(dr[n + 2], wv[n + 2], z2);
      z3 = fmaf(dr[n + 3], wv[n + 3], z3);
    }
    float z = (z0 + z1) + (z2 + z3);
    float dl = (z > 20.f) ? z : __logf(1.f + __expf(z));
    delta[(size_t)(r0 + j) * DIM + d] = f2bf(dl);
  }
}

// ---------------- chunked scan, pass 1: per-chunk (sumd, q) -> bf16 ----------------
__global__ __launch_bounds__(256) void scan_pass1(const unsigned short* __restrict__ xc,
                                                  const unsigned short* __restrict__ dl,
                                                  const float* __restrict__ xd,
                                                  unsigned short* __restrict__ sdbuf,
                                                  unsigned short* __restrict__ qbuf) {
  const int wid = __builtin_amdgcn_readfirstlane((int)(threadIdx.x >> 6));
  const int lane = threadIdx.x & 63;
  const int W = blockIdx.x * 4 + wid;
  const int dg = W & 31;
  const int rest = W >> 5;
  const int c = rest % NCH;
  const int b = rest / NCH;
  const int d = dg * 64 + lane;
  const int t0 = c * CS;
  const int nst = (t0 + CS <= LC) ? CS : (LC - t0);

  float2v A2L[8];
#pragma unroll
  for (int i = 0; i < 8; ++i)
    A2L[i] = (float2v){AeT[2 * i] * LOG2E, AeT[2 * i + 1] * LOG2E};

  float2v h2[8];
#pragma unroll
  for (int i = 0; i < 8; ++i) h2[i] = (float2v){0.f, 0.f};
  float sumd = 0.f;

  const size_t row0 = (size_t)b * LC + t0;
  const float* xdb = xd + row0 * 48 + 16;            // B cols (uniform -> s_load)
  const unsigned short* xcp = xc + row0 * DIM + d;
  const unsigned short* dp  = dl + row0 * DIM + d;

  float2v BA[8], BB[8];
#pragma unroll
  for (int j = 0; j < 8; ++j) BA[j] = *(const float2v*)(xdb + 2 * j);
  float d0v = bf2f(dp[0]), x0v = bf2f(xcp[0]);

  auto step = [&](const float2v (&Bv)[8], float dlt, float xcv) {
    sumd += dlt;
    float2v dlt2 = (float2v){dlt, dlt};
    float2v xcv2 = (float2v){xcv, xcv};
#pragma unroll
    for (int i = 0; i < 8; ++i) {
      float2v arg = pk_mul_vv(dlt2, A2L[i]);
      float e0 = exp2_raw(arg.x), e1 = exp2_raw(arg.y);
      float2v e2 = (float2v){e0, e1};
      h2[i] = pk_fma_vvv(h2[i], e2, pk_mul_sv(Bv[i], xcv2));
    }
  };

  for (int s = 0; s < nst; s += 2) {
    int s1 = (s + 1 < nst) ? s + 1 : s;
#pragma unroll
    for (int j = 0; j < 8; ++j) BB[j] = *(const float2v*)(xdb + (size_t)s1 * 48 + 2 * j);
    float d1v = bf2f(dp[(size_t)s1 * DIM]);
    float x1v = bf2f(xcp[(size_t)s1 * DIM]);
    step(BA, d0v, x0v);
    if (s + 1 >= nst) break;
    int s2 = (s + 2 < nst) ? s + 2 : s + 1;
#pragma unroll
    for (int j = 0; j < 8; ++j) BA[j] = *(const float2v*)(xdb + (size_t)s2 * 48 + 2 * j);
    d0v = bf2f(dp[(size_t)s2 * DIM]);
    x0v = bf2f(xcp[(size_t)s2 * DIM]);
    step(BB, d1v, x1v);
  }

  sdbuf[((size_t)(b * NCH + c) << 11) + d] = f2bf(sumd);
  const size_t base = ((size_t)(b * NCH + c) * 16) * 2048 + d;
#pragma unroll
  for (int i = 0; i < 8; ++i) {
    qbuf[base + ((size_t)(2 * i) << 11)]     = f2bf(h2[i].x);
    qbuf[base + ((size_t)(2 * i + 1) << 11)] = f2bf(h2[i].y);
  }
}

// ---------------- boundary scan: h across chunks; writes h_init over q ----------------
__global__ __launch_bounds__(64) void scan_boundary(const unsigned short* __restrict__ sdbuf,
                                                    unsigned short* __restrict__ qbuf) {
  const int d = blockIdx.x * 64 + threadIdx.x;
  const int b = blockIdx.y;
  float h[16];
#pragma unroll
  for (int n = 0; n < 16; ++n) h[n] = 0.f;
  for (int c = 0; c < NCH; ++c) {
    const float sd = bf2f(sdbuf[((size_t)(b * NCH + c) << 11) + d]);
    const size_t base = ((size_t)(b * NCH + c) * 16) * 2048 + d;
    float qv[16];
#pragma unroll
    for (int n = 0; n < 16; ++n) qv[n] = bf2f(qbuf[base + ((size_t)n << 11)]);
#pragma unroll
    for (int n = 0; n < 16; ++n) {
      float Pv = __expf(sd * AeT[n]);
      qbuf[base + ((size_t)n << 11)] = f2bf(h[n]);   // h at chunk start
      h[n] = fmaf(Pv, h[n], qv[n]);
    }
  }
}

// ---------------- chunked scan, pass 2: recompute with h_init, emit y ----------------
__global__ __launch_bounds__(256) void scan_pass2(const unsigned short* __restrict__ xc,
                                                  const unsigned short* __restrict__ dl,
                                                  const float* __restrict__ xd,
                                                  const unsigned short* __restrict__ hinit,
                                                  unsigned short* __restrict__ y) {
  const int wid = __builtin_amdgcn_readfirstlane((int)(threadIdx.x >> 6));
  const int lane = threadIdx.x & 63;
  const int W = blockIdx.x * 4 + wid;
  const int dg = W & 31;
  const int rest = W >> 5;
  const int c = rest % NCH;
  const int b = rest / NCH;
  const int d = dg * 64 + lane;
  const int t0 = c * CS;
  const int nst = (t0 + CS <= LC) ? CS : (LC - t0);

  float2v A2L[8];
#pragma unroll
  for (int i = 0; i < 8; ++i)
    A2L[i] = (float2v){AeT[2 * i] * LOG2E, AeT[2 * i + 1] * LOG2E};

  const size_t base = ((size_t)(b * NCH + c) * 16) * 2048 + d;
  float2v h2[8];
#pragma unroll
  for (int i = 0; i < 8; ++i)
    h2[i] = (float2v){bf2f(hinit[base + ((size_t)(2 * i) << 11)]),
                      bf2f(hinit[base + ((size_t)(2 * i + 1) << 11)])};

  const size_t row0 = (size_t)b * LC + t0;
  const float* xdb = xd + row0 * 48 + 16;            // B at [j], C at [16+j]
  const unsigned short* xcp = xc + row0 * DIM + d;
  const unsigned short* dp  = dl + row0 * DIM + d;
  unsigned short* yp = y + row0 * DIM + d;

  float2v BA[8], CA[8], BB[8], CB[8];
#pragma unroll
  for (int j = 0; j < 8; ++j) {
    BA[j] = *(const float2v*)(xdb + 2 * j);
    CA[j] = *(const float2v*)(xdb + 16 + 2 * j);
  }
  float d0v = bf2f(dp[0]), x0v = bf2f(xcp[0]);

  auto step = [&](const float2v (&Bv)[8], const float2v (&Cv)[8], float dlt, float xcv, int s) {
    float2v dlt2 = (float2v){dlt, dlt};
    float2v xcv2 = (float2v){xcv, xcv};
    float2v y2[4];
#pragma unroll
    for (int i = 0; i < 4; ++i) y2[i] = (float2v){0.f, 0.f};
#pragma unroll
    for (int i = 0; i < 8; ++i) {
      float2v arg = pk_mul_vv(dlt2, A2L[i]);
      float e0 = exp2_raw(arg.x), e1 = exp2_raw(arg.y);
      float2v e2 = (float2v){e0, e1};
      h2[i] = pk_fma_vvv(h2[i], e2, pk_mul_sv(Bv[i], xcv2));
      y2[i & 3] = pk_fma_vsv(h2[i], Cv[i], y2[i & 3]);
    }
    float2v s01 = pk_add_vv(y2[0], y2[1]);
    float2v s23 = pk_add_vv(y2[2], y2[3]);
    float2v st = pk_add_vv(s01, s23);
    yp[(size_t)s * DIM] = f2bf(st.x + st.y);
  };

  for (int s = 0; s < nst; s += 2) {
    int s1 = (s + 1 < nst) ? s + 1 : s;
#pragma unroll
    for (int j = 0; j < 8; ++j) {
      BB[j] = *(const float2v*)(xdb + (size_t)s1 * 48 + 2 * j);
      CB[j] = *(const float2v*)(xdb + (size_t)s1 * 48 + 16 + 2 * j);
    }
    float d1v = bf2f(dp[(size_t)s1 * DIM]);
    float x1v = bf2f(xcp[(size_t)s1 * DIM]);
    step(BA, CA, d0v, x0v, s);
    if (s + 1 >= nst) break;
    int s2 = (s + 2 < nst) ? s + 2 : s + 1;
#pragma unroll
    for (int j = 0; j < 8; ++j) {
      BA[j] = *(const float2v*)(xdb + (size_t)s2 * 48 + 2 * j);
      CA[j] = *(const float2v*)(xdb + (size_t)s2 * 48 + 16 + 2 * j);
    }
    d0v = bf2f(dp[(size_t)s2 * DIM]);
    x0v = bf2f(xcp[(size_t)s2 * DIM]);
    step(BB, CB, d1v, x1v, s + 1);
  }
}

// ---------------- launch ----------------
extern "C" void kernel_launch(void* const* d_in, const int* in_sizes, int n_in,
                              void* d_out, int out_size, void* d_ws, size_t ws_size,
                              hipStream_t stream) {
  const float* x      = (const float*)d_in[0];
  const float* W_in   = (const float*)d_in[1];
  const float* b_in   = (const float*)d_in[2];
  const float* conv_w = (const float*)d_in[3];
  const float* conv_b = (const float*)d_in[4];
  const float* W_x    = (const float*)d_in[5];
  const float* W_dt   = (const float*)d_in[6];
  const float* b_dt   = (const float*)d_in[7];
  const float* W_out  = (const float*)d_in[8];
  const float* b_out  = (const float*)d_in[9];

  char* w = (char*)d_ws;
  // region 0 (67.63 MB): xp (LPAD layout) -> delta [M2P][DIM] -> y (in-place over delta)
  unsigned short* xp    = (unsigned short*)w;
  unsigned short* delta = (unsigned short*)w;
  unsigned short* ybuf  = (unsigned short*)w;
  size_t off = (size_t)M2P * DIM * 2;                                  // 67,633,152
  unsigned short* xcb  = (unsigned short*)(w + off); off += (size_t)M2P * DIM * 2;
  size_t xA_off = off;                                                 // 135,266,304
  unsigned short* xA   = (unsigned short*)(w + off); off += (size_t)16384 * 1024 * 2;
  unsigned short* wInB = (unsigned short*)(w + off); off += (size_t)2048 * 1024 * 2;
  unsigned short* wOutB= (unsigned short*)(w + off); off += (size_t)1024 * 2048 * 2;
  unsigned short* wXB  = (unsigned short*)(w + off); off += (size_t)128 * 2048 * 2;
  float* xdbl          = (float*)(w + off);          off += (size_t)M2 * 48 * 4;
  // sdbuf (2.13 MB bf16) + qbuf (34.08 MB bf16) reuse xA+wInB region (dead after gemm1)
  unsigned short* sdbuf = (unsigned short*)(w + xA_off);
  unsigned short* qbuf  = (unsigned short*)(w + xA_off + (size_t)B8 * NCH * 2048 * 2);
  (void)ws_size; (void)in_sizes; (void)n_in; (void)out_size;

  cvt_f32_bf16<<<8192, 256, 0, stream>>>(x, xA, 2097152);
  cvt_f32_bf16<<<1024, 256, 0, stream>>>(W_in, wInB, 262144);
  cvt_f32_bf16<<<1024, 256, 0, stream>>>(W_out, wOutB, 262144);
  cvt_f32_bf16<<<48,   256, 0, stream>>>(W_x, wXB, 12288);
  zero_pads<<<48, 256, 0, stream>>>(xp);

  // deep-pipelined GEMMs: grid = 8 * LX * NBN (XCD-banded remap inside)
  gemm8p<0, 64, 8, 8, 32><<<512, 512, 0, stream>>>(xA, wInB, b_in, xp);
  conv_kernel<<<dim3(LC, B8), 256, 0, stream>>>(xp, conv_w, conv_b, xcb);
  gemm_bt<129, 1, 17><<<136, 256, 0, stream>>>(xcb, wXB, xdbl, 2048);
  delta_kernel<<<dim3(2051, 8), 256, 0, stream>>>(xdbl, W_dt, b_dt, delta);

  scan_pass1<<<4160, 256, 0, stream>>>(xcb, delta, xdbl, sdbuf, qbuf);
  scan_boundary<<<dim3(32, B8), 64, 0, stream>>>(sdbuf, qbuf);
  scan_pass2<<<4160, 256, 0, stream>>>(xcb, delta, xdbl, qbuf, ybuf);

  gemm8p<2, 65, 4, 9, 64><<<288, 512, 0, stream>>>(ybuf, wOutB, b_out, (float*)d_out);
}